// Round 22
// baseline (29.632 us; speedup 1.0000x reference)
//
#include <hip/hip_runtime.h>
#include <hip/hip_bf16.h>

#define NB 16
#define NN 256
#define NH 8
#define ND 64
#define NT 5
#define HD 512   // NH*ND

typedef __bf16 bf16x8 __attribute__((ext_vector_type(8)));
typedef __bf16 bf16x4 __attribute__((ext_vector_type(4)));
typedef float  f32x4  __attribute__((ext_vector_type(4)));
typedef int    i32x4  __attribute__((ext_vector_type(4)));

__device__ __forceinline__ bf16x8 cvt8(f32x4 a, f32x4 b) {
    bf16x8 r;
    r[0] = (__bf16)a[0]; r[1] = (__bf16)a[1]; r[2] = (__bf16)a[2]; r[3] = (__bf16)a[3];
    r[4] = (__bf16)b[0]; r[5] = (__bf16)b[1]; r[6] = (__bf16)b[2]; r[7] = (__bf16)b[3];
    return r;
}

// fire-and-forget global->LDS: lane l writes LDS[base + l*16]; src addr is per-lane.
__device__ __forceinline__ void stage16(const void* g, void* l) {
    __builtin_amdgcn_global_load_lds(
        (const __attribute__((address_space(1))) void*)g,
        (__attribute__((address_space(3))) void*)l,
        16, 0, 0);
}

// Transpose a[(h*64+dd)*64*5 + e*5 + t] -> wt[h][t][e][dd] (bf16). Output-linear.
__global__ void prep_w_kernel(const float* __restrict__ a, __bf16* __restrict__ wt) {
    const int o8 = (blockIdx.x * 256 + threadIdx.x) * 8;
    if (o8 >= NH * ND * ND * NT) return;
    const int dd0 = o8 & 63;
    const int e   = (o8 >> 6) & 63;
    const int ht  = o8 >> 12;       // h*NT + t
    const int t   = ht % NT;
    const int h   = ht / NT;
    bf16x8 v;
    #pragma unroll
    for (int j = 0; j < 8; ++j)
        v[j] = (__bf16)a[((size_t)(h * ND + dd0 + j) * ND + e) * NT + t];
    *reinterpret_cast<bf16x8*>(wt + o8) = v;
}

// LDS layout (bytes). W region [0,40960) reused after prologue for P0/P1/S2.
// E removed from LDS entirely (per-lane-private data -> registers).
#define LW   0
#define LP0  0
#define LP1  10240
#define LS2  20480
#define LS0  40960
#define LS1  45056
// declared 49152 (48 KB); occupancy stays VGPR-bound at 2 blocks/CU (16 waves)

// ================= fused: block = (b, h, j-half, i-half); 8 i-tiles =================
// R19 skeleton, E-in-registers variant: edges for all 8 windows loaded at prologue
// (one burst, retired by the existing vmcnt(0)); per-window staging = S only (w<4).
__global__ __launch_bounds__(512, 2) void mhea_fused(
    const float* __restrict__ src, const float* __restrict__ dst,
    const __bf16* __restrict__ wt, const int* __restrict__ edges,
    float* __restrict__ out)
{
    __shared__ alignas(16) unsigned char Lb[49152];

    const int bid = blockIdx.x;
    const int wg  = (bid & 7) * 64 + (bid >> 3);    // XCD-chunked, bijective (512 = 8*64)
    const int b   = wg >> 5;          // 0..15
    const int h   = (wg >> 2) & 7;
    const int jh  = (wg >> 1) & 1;
    const int ih  = wg & 1;
    const int j0  = jh * 128;
    const int ib0 = ih * 128;

    const int tid = threadIdx.x;
    const int w   = tid >> 6;    // wave 0..7
    const int l   = tid & 63;
    const int il  = l & 15;
    const int kg  = l >> 4;      // lane k-group 0..3

    const int et  = w & 3;       // phase-1 e-tile (0..3)
    const int tl  = w >> 2;      // t-half: 0 -> t{0,1,2}, 1 -> t{3,4}
    const int t0  = tl * 3;
    const int ntl = 3 - tl;      // 3 or 2

    const int SO[3] = {LS0, LS1, LS2};

    // ---------------- prologue ----------------
    // D-row raw loads issued FIRST; conversion deferred past the staging burst.
    f32x4 q0, q1, q2, q3;
    {
        const float* dp = dst + ((size_t)(b * NN + j0 + w * 16 + il)) * HD + h * ND;
        q0 = *reinterpret_cast<const f32x4*>(dp + kg * 8);
        q1 = *reinterpret_cast<const f32x4*>(dp + kg * 8 + 4);
        q2 = *reinterpret_cast<const f32x4*>(dp + 32 + kg * 8);
        q3 = *reinterpret_cast<const f32x4*>(dp + 36 + kg * 8);
    }
    // Edge int4s for ALL 8 windows -> registers (8 independent dwordx4, one burst;
    // each lane's data is private: row il, cols j0 + w*16 + kg*4 .. +3).
    i32x4 ceall[8];
    #pragma unroll
    for (int k = 0; k < 8; ++k)
        ceall[k] = *reinterpret_cast<const i32x4*>(
            edges + ((size_t)(b * NN + ib0 + k * 16 + il)) * NN + j0 + w * 16 + kg * 4);

    // W staging: 40 x 1KB (5/wave), pre-swizzled source.
    {
        const __bf16* wbase = wt + (size_t)(h * NT) * ND * ND;
        #pragma unroll
        for (int k = 0; k < 5; ++k) {
            const int idx = w * 5 + k;           // 0..39
            const int t   = idx >> 3;
            const int sub = idx & 7;
            const int e   = sub * 8 + (l >> 3);
            const int c   = (l & 7) ^ (e & 7);
            stage16(wbase + ((size_t)t * ND + e) * ND + c * 8,
                    Lb + LW + t * 8192 + sub * 1024);
        }
    }
    // S tiles 0,1 (4 x 1KB each; waves 0-3, 1 op per tile)
    if (w < 4) {
        #pragma unroll
        for (int p = 0; p < 2; ++p) {
            const int row = w * 4 + (l >> 4);
            const int c   = (l & 15) ^ (row & 7);
            stage16(src + ((size_t)(b * NN + ib0 + p * 16 + row)) * HD + h * ND + c * 4,
                    Lb + SO[p] + w * 1024);
        }
    }

    // convert D-frags (loads overlapped with the staging burst)
    bf16x8 cb0 = cvt8(q0, q1);
    bf16x8 cb1 = cvt8(q2, q3);

    asm volatile("s_waitcnt vmcnt(0)" ::: "memory");
    __builtin_amdgcn_sched_barrier(0);
    __builtin_amdgcn_s_barrier();        // W, S0/1 visible; D/edge loads retired

    // W-frags -> registers (this wave's e-tile, its t-subset)
    bf16x8 wa[3][2];
    #pragma unroll
    for (int tt = 0; tt < 3; ++tt) {
        if (tt < ntl) {
            const int t = t0 + tt;
            #pragma unroll
            for (int ks = 0; ks < 2; ++ks)
                wa[tt][ks] = *reinterpret_cast<const bf16x8*>(
                    Lb + LW + t * 8192 + (et * 16 + il) * 128
                       + (((ks * 4 + kg) ^ (il & 7)) << 4));
        }
    }
    asm volatile("s_waitcnt lgkmcnt(0)" ::: "memory");
    __builtin_amdgcn_sched_barrier(0);
    __builtin_amdgcn_s_barrier();        // W reads done -> region reusable (P/S2)

    // ---------------- main loop: 8 i-tiles, ONE barrier each ----------------
    #pragma unroll
    for (int k = 0; k < 8; ++k) {
        const float* Sc = (const float*)(Lb + SO[k % 3]);
        __bf16*      Pc = (__bf16*)     (Lb + ((k & 1) ? LP1 : LP0));

        // a) stage tile k+2's src (waves 0-3; retired at barrier k+1)
        if (k < 6 && w < 4) {
            const int i2  = ib0 + (k + 2) * 16;
            const int row = w * 4 + (l >> 4);
            const int c   = (l & 15) ^ (row & 7);
            stage16(src + ((size_t)(b * NN + i2 + row)) * HD + h * ND + c * 4,
                    Lb + SO[(k + 2) % 3] + w * 1024);
        }

        // b) edge int4 for this iter: already in registers (static index post-unroll)
        const i32x4 ce = ceall[k];

        // c) phase 1: P_t[i, e-tile et] for this wave's t-subset
        {
            f32x4 a0 = *reinterpret_cast<const f32x4*>(&Sc[il * ND + (((2 * kg + 0) ^ (il & 7)) << 2)]);
            f32x4 a1 = *reinterpret_cast<const f32x4*>(&Sc[il * ND + (((2 * kg + 1) ^ (il & 7)) << 2)]);
            f32x4 a2 = *reinterpret_cast<const f32x4*>(&Sc[il * ND + (((8 + 2 * kg) ^ (il & 7)) << 2)]);
            f32x4 a3 = *reinterpret_cast<const f32x4*>(&Sc[il * ND + (((9 + 2 * kg) ^ (il & 7)) << 2)]);
            bf16x8 bf0 = cvt8(a0, a1);
            bf16x8 bf1 = cvt8(a2, a3);
            __builtin_amdgcn_s_setprio(1);
            #pragma unroll
            for (int tt = 0; tt < 3; ++tt) {
                if (tt < ntl) {
                    const int t = t0 + tt;
                    // A = W^T rows (m=e), B = src (n=i): lane holds e=et*16+kg*4+r, i=il
                    f32x4 pacc = {0.f, 0.f, 0.f, 0.f};
                    pacc = __builtin_amdgcn_mfma_f32_16x16x32_bf16(wa[tt][0], bf0, pacc, 0, 0, 0);
                    pacc = __builtin_amdgcn_mfma_f32_16x16x32_bf16(wa[tt][1], bf1, pacc, 0, 0, 0);
                    bf16x4 pk;
                    pk[0] = (__bf16)pacc[0];
                    pk[1] = (__bf16)pacc[1];
                    pk[2] = (__bf16)pacc[2];
                    pk[3] = (__bf16)pacc[3];
                    const int elem = (et * 16 + kg * 4) ^ ((il & 7) << 3);
                    *reinterpret_cast<bf16x4*>(Pc + t * 1024 + il * ND + elem) = pk;
                }
            }
            __builtin_amdgcn_s_setprio(0);
        }

        // d) counted-wait barrier.
        //    w<4 outstanding (newest first): [S_{k+2}, store_{k-1}] -> retire S_{k+1}
        //    with vmcnt(2); tail (no staging): [store_{k-1}] -> vmcnt(1).
        //    w>=4 issue no staging: nothing to retire; lgkmcnt(0) for P visibility.
        if (w < 4) {
            if (k < 6) { asm volatile("s_waitcnt vmcnt(2) lgkmcnt(0)" ::: "memory"); }
            else       { asm volatile("s_waitcnt vmcnt(1) lgkmcnt(0)" ::: "memory"); }
        } else {
            asm volatile("s_waitcnt lgkmcnt(0)" ::: "memory");
        }
        __builtin_amdgcn_sched_barrier(0);
        __builtin_amdgcn_s_barrier();

        // e) phase 2: this wave's 16-j tile vs all 16 i of the tile
        {
            bf16x8 pa[NT][2];
            #pragma unroll
            for (int t = 0; t < NT; ++t)
                #pragma unroll
                for (int ks = 0; ks < 2; ++ks)
                    pa[t][ks] = *reinterpret_cast<const bf16x8*>(
                        Pc + t * 1024 + il * ND + (((ks * 4 + kg) ^ (il & 7)) << 3));

            __builtin_amdgcn_s_setprio(1);
            f32x4 acc[NT];
            #pragma unroll
            for (int t = 0; t < NT; ++t) {
                acc[t] = (f32x4){0.f, 0.f, 0.f, 0.f};
                // A = dst rows (m=j), B = P (n=i): lane holds j=w*16+kg*4+r, i=il
                acc[t] = __builtin_amdgcn_mfma_f32_16x16x32_bf16(cb0, pa[t][0], acc[t], 0, 0, 0);
                acc[t] = __builtin_amdgcn_mfma_f32_16x16x32_bf16(cb1, pa[t][1], acc[t], 0, 0, 0);
            }
            __builtin_amdgcn_s_setprio(0);

            f32x4 o;
            #pragma unroll
            for (int r = 0; r < 4; ++r) {
                const int ev = ce[r];
                float x;
                if (ev < 0) { x = -1e10f; }
                else {
                    x = (ev == 0) ? acc[0][r]
                      : (ev == 1) ? acc[1][r]
                      : (ev == 2) ? acc[2][r]
                      : (ev == 3) ? acc[3][r]
                      :             acc[4][r];
                }
                o[r] = (x >= 0.f) ? x : 0.2f * x;
            }
            *reinterpret_cast<f32x4*>(
                out + ((size_t)(b * NH + h) * NN + ib0 + k * 16 + il) * NN
                    + j0 + w * 16 + kg * 4) = o;
        }
        // Hazards unchanged from R19: P double-buffer, S slot rotation separated
        // by the barrier above; phase-2 P-reads drained by next barrier's lgkmcnt(0).
    }
}

// ---------------- fallback (ws too small): fused 1-wave kernel, araw path ----------------
__global__ __launch_bounds__(64, 3) void mhea_fused_fallback(
    const float* __restrict__ src, const float* __restrict__ dst,
    const float* __restrict__ araw, const int* __restrict__ edges,
    float* __restrict__ out)
{
    __shared__ __bf16 Plds[NT * 16 * 64];

    const int it = blockIdx.x;
    const int h  = blockIdx.y;
    const int b  = blockIdx.z;
    const int i0 = it * 16;

    const int l  = threadIdx.x & 63;
    const int il = l & 15;
    const int kg = l >> 4;

    const float* dbase = dst + (size_t)b * NN * HD + h * ND;
    const int*   erow  = edges + ((size_t)b * NN + i0 + il) * NN;
    const float* sbase = src + (size_t)(b * NN + i0 + il) * HD + h * ND;

    f32x4 s0 = *reinterpret_cast<const f32x4*>(sbase + kg * 8);
    f32x4 s1 = *reinterpret_cast<const f32x4*>(sbase + kg * 8 + 4);
    f32x4 s2 = *reinterpret_cast<const f32x4*>(sbase + 32 + kg * 8);
    f32x4 s3 = *reinterpret_cast<const f32x4*>(sbase + 36 + kg * 8);
    bf16x8 af0 = cvt8(s0, s1);
    bf16x8 af1 = cvt8(s2, s3);

    #pragma unroll
    for (int t = 0; t < NT; ++t) {
        #pragma unroll
        for (int et = 0; et < 4; ++et) {
            bf16x8 w0, w1;
            #pragma unroll
            for (int jj = 0; jj < 8; ++jj) {
                const int ee = et * 16 + il;
                w0[jj] = (__bf16)araw[((size_t)(h * ND + kg * 8 + jj) * ND + ee) * NT + t];
                w1[jj] = (__bf16)araw[((size_t)(h * ND + kg * 8 + jj + 32) * ND + ee) * NT + t];
            }
            f32x4 pacc = {0.f, 0.f, 0.f, 0.f};
            pacc = __builtin_amdgcn_mfma_f32_16x16x32_bf16(w0, af0, pacc, 0, 0, 0);
            pacc = __builtin_amdgcn_mfma_f32_16x16x32_bf16(w1, af1, pacc, 0, 0, 0);
            bf16x4 pk;
            pk[0] = (__bf16)pacc[0];
            pk[1] = (__bf16)pacc[1];
            pk[2] = (__bf16)pacc[2];
            pk[3] = (__bf16)pacc[3];
            const int elem = (et * 16 + kg * 4) ^ ((il & 7) << 3);
            *reinterpret_cast<bf16x4*>(&Plds[t * 1024 + il * 64 + elem]) = pk;
        }
    }

    bf16x8 pa[NT][2];
    #pragma unroll
    for (int t = 0; t < NT; ++t) {
        #pragma unroll
        for (int ks = 0; ks < 2; ++ks) {
            const int elem = (ks * 32 + kg * 8) ^ ((il & 7) << 3);
            pa[t][ks] = *reinterpret_cast<const bf16x8*>(&Plds[t * 1024 + il * 64 + elem]);
        }
    }

    float* obase = out + (((size_t)(b * NH + h)) * NN + i0 + il) * NN;

    for (int jt = 0; jt < 16; ++jt) {
        const float* np = dbase + (size_t)(jt * 16 + il) * HD + kg * 8;
        f32x4 d0 = *reinterpret_cast<const f32x4*>(np);
        f32x4 d1 = *reinterpret_cast<const f32x4*>(np + 4);
        f32x4 d2 = *reinterpret_cast<const f32x4*>(np + 32);
        f32x4 d3 = *reinterpret_cast<const f32x4*>(np + 36);
        i32x4 ce = *reinterpret_cast<const i32x4*>(erow + jt * 16 + kg * 4);
        const bf16x8 cb0 = cvt8(d0, d1);
        const bf16x8 cb1 = cvt8(d2, d3);
        f32x4 acc[NT];
        #pragma unroll
        for (int t = 0; t < NT; ++t) {
            acc[t] = (f32x4){0.f, 0.f, 0.f, 0.f};
            acc[t] = __builtin_amdgcn_mfma_f32_16x16x32_bf16(cb0, pa[t][0], acc[t], 0, 0, 0);
            acc[t] = __builtin_amdgcn_mfma_f32_16x16x32_bf16(cb1, pa[t][1], acc[t], 0, 0, 0);
        }
        f32x4 o;
        #pragma unroll
        for (int r = 0; r < 4; ++r) {
            const int ev = ce[r];
            float x;
            if (ev < 0) { x = -1e10f; }
            else {
                x = (ev == 0) ? acc[0][r]
                  : (ev == 1) ? acc[1][r]
                  : (ev == 2) ? acc[2][r]
                  : (ev == 3) ? acc[3][r]
                  :             acc[4][r];
            }
            o[r] = (x >= 0.f) ? x : 0.2f * x;
        }
        *reinterpret_cast<f32x4*>(obase + jt * 16 + kg * 4) = o;
    }
}

extern "C" void kernel_launch(void* const* d_in, const int* in_sizes, int n_in,
                              void* d_out, int out_size, void* d_ws, size_t ws_size,
                              hipStream_t stream) {
    const float* src   = (const float*)d_in[0];
    const float* dst   = (const float*)d_in[1];
    const float* a     = (const float*)d_in[2];
    const int*   edges = (const int*)d_in[3];
    float* out = (float*)d_out;

    const size_t wt_bytes = (size_t)NH * NT * ND * ND * sizeof(__bf16);  // 320 KB

    if (ws_size >= wt_bytes) {
        __bf16* wt = (__bf16*)d_ws;
        const int total = NH * ND * ND * NT;           // 163840
        prep_w_kernel<<<(total / 8 + 255) / 256, 256, 0, stream>>>(a, wt);
        mhea_fused<<<512, 512, 0, stream>>>(src, dst, wt, edges, out);
    } else {
        mhea_fused_fallback<<<dim3(NN / 16, NH, NB), 64, 0, stream>>>(
            src, dst, a, edges, out);
    }
}

// Round 23
// 27.299 us; speedup vs baseline: 1.0855x; 1.0855x over previous
//
#include <hip/hip_runtime.h>
#include <hip/hip_bf16.h>

#define NB 16
#define NN 256
#define NH 8
#define ND 64
#define NT 5
#define HD 512   // NH*ND

typedef __bf16 bf16x8 __attribute__((ext_vector_type(8)));
typedef __bf16 bf16x4 __attribute__((ext_vector_type(4)));
typedef float  f32x4  __attribute__((ext_vector_type(4)));
typedef int    i32x4  __attribute__((ext_vector_type(4)));

__device__ __forceinline__ bf16x8 cvt8(f32x4 a, f32x4 b) {
    bf16x8 r;
    r[0] = (__bf16)a[0]; r[1] = (__bf16)a[1]; r[2] = (__bf16)a[2]; r[3] = (__bf16)a[3];
    r[4] = (__bf16)b[0]; r[5] = (__bf16)b[1]; r[6] = (__bf16)b[2]; r[7] = (__bf16)b[3];
    return r;
}

// fire-and-forget global->LDS: lane l writes LDS[base + l*16]; src addr is per-lane.
__device__ __forceinline__ void stage16(const void* g, void* l) {
    __builtin_amdgcn_global_load_lds(
        (const __attribute__((address_space(1))) void*)g,
        (__attribute__((address_space(3))) void*)l,
        16, 0, 0);
}

// Transpose a[(h*64+dd)*64*5 + e*5 + t] -> wt[h][t][e][dd] (bf16).
// OUTPUT-linear: one coalesced 16B write per thread; 8 scattered 4B reads
// (L2/L3-absorbed).
__global__ void prep_w_kernel(const float* __restrict__ a, __bf16* __restrict__ wt) {
    const int o8 = (blockIdx.x * 256 + threadIdx.x) * 8;
    if (o8 >= NH * ND * ND * NT) return;
    const int dd0 = o8 & 63;
    const int e   = (o8 >> 6) & 63;
    const int ht  = o8 >> 12;       // h*NT + t
    const int t   = ht % NT;
    const int h   = ht / NT;
    bf16x8 v;
    #pragma unroll
    for (int j = 0; j < 8; ++j)
        v[j] = (__bf16)a[((size_t)(h * ND + dd0 + j) * ND + e) * NT + t];
    *reinterpret_cast<bf16x8*>(wt + o8) = v;
}

// LDS layout (bytes). W region [0,40960) is reused after prologue for P0/P1/S2/E2.
#define LW   0
#define LP0  0
#define LP1  10240
#define LS2  20480
#define LE2  24576
#define LS0  40960
#define LS1  45056
#define LE0  49152
#define LE1  57344
// total 65536 (64 KB) -> 2 blocks/CU (16 waves/CU)

// ================= fused: block = (b, h, j-half, i-half); 8 i-tiles =================
// Verified-best skeleton (R17/R19): 8 homogeneous waves, all-DMA staging,
// triple-buffered S/E, counted vmcnt + raw barriers, P double-buffered,
// 1 barrier/iter, setprio around MFMA clusters, XCD-chunked block swizzle.
__global__ __launch_bounds__(512, 2) void mhea_fused(
    const float* __restrict__ src, const float* __restrict__ dst,
    const __bf16* __restrict__ wt, const int* __restrict__ edges,
    float* __restrict__ out)
{
    __shared__ alignas(16) unsigned char Lb[65536];

    const int bid = blockIdx.x;
    const int wg  = (bid & 7) * 64 + (bid >> 3);    // XCD-chunked, bijective (512 = 8*64)
    const int b   = wg >> 5;          // 0..15
    const int h   = (wg >> 2) & 7;
    const int jh  = (wg >> 1) & 1;
    const int ih  = wg & 1;
    const int j0  = jh * 128;
    const int ib0 = ih * 128;

    const int tid = threadIdx.x;
    const int w   = tid >> 6;    // wave 0..7
    const int l   = tid & 63;
    const int il  = l & 15;
    const int kg  = l >> 4;      // lane k-group 0..3

    const int et  = w & 3;       // phase-1 e-tile (0..3)
    const int tl  = w >> 2;      // t-half: 0 -> t{0,1,2}, 1 -> t{3,4}
    const int t0  = tl * 3;
    const int ntl = 3 - tl;      // 3 or 2

    const int SO[3] = {LS0, LS1, LS2};
    const int EO[3] = {LE0, LE1, LE2};

    // ---------------- prologue ----------------
    // D-row raw loads issued FIRST; conversion deferred past the staging burst.
    f32x4 q0, q1, q2, q3;
    {
        const float* dp = dst + ((size_t)(b * NN + j0 + w * 16 + il)) * HD + h * ND;
        q0 = *reinterpret_cast<const f32x4*>(dp + kg * 8);
        q1 = *reinterpret_cast<const f32x4*>(dp + kg * 8 + 4);
        q2 = *reinterpret_cast<const f32x4*>(dp + 32 + kg * 8);
        q3 = *reinterpret_cast<const f32x4*>(dp + 36 + kg * 8);
    }

    // W staging: 40 x 1KB (5/wave), pre-swizzled source.
    {
        const __bf16* wbase = wt + (size_t)(h * NT) * ND * ND;
        #pragma unroll
        for (int k = 0; k < 5; ++k) {
            const int idx = w * 5 + k;           // 0..39
            const int t   = idx >> 3;
            const int sub = idx & 7;
            const int e   = sub * 8 + (l >> 3);
            const int c   = (l & 7) ^ (e & 7);
            stage16(wbase + ((size_t)t * ND + e) * ND + c * 8,
                    Lb + LW + t * 8192 + sub * 1024);
        }
    }
    // S tiles 0,1 (4 x 1KB each; waves 0-3, 1 op per tile)
    if (w < 4) {
        #pragma unroll
        for (int p = 0; p < 2; ++p) {
            const int row = w * 4 + (l >> 4);
            const int c   = (l & 15) ^ (row & 7);
            stage16(src + ((size_t)(b * NN + ib0 + p * 16 + row)) * HD + h * ND + c * 4,
                    Lb + SO[p] + w * 1024);
        }
    }
    // E tiles 0,1 (8 x 1KB each; all waves, 1 op per tile). Row = 128 ints = 512B.
    #pragma unroll
    for (int p = 0; p < 2; ++p) {
        const int row = w * 2 + (l >> 5);
        const int c   = (l & 31) ^ (row & 7);
        stage16(edges + ((size_t)(b * NN + ib0 + p * 16 + row)) * NN + j0 + c * 4,
                Lb + EO[p] + w * 1024);
    }

    // convert D-frags (loads overlapped with the staging burst)
    bf16x8 cb0 = cvt8(q0, q1);
    bf16x8 cb1 = cvt8(q2, q3);

    asm volatile("s_waitcnt vmcnt(0)" ::: "memory");
    __builtin_amdgcn_sched_barrier(0);
    __builtin_amdgcn_s_barrier();        // W, S0/1, E0/1 visible

    // W-frags -> registers (this wave's e-tile, its t-subset)
    bf16x8 wa[3][2];
    #pragma unroll
    for (int tt = 0; tt < 3; ++tt) {
        if (tt < ntl) {
            const int t = t0 + tt;
            #pragma unroll
            for (int ks = 0; ks < 2; ++ks)
                wa[tt][ks] = *reinterpret_cast<const bf16x8*>(
                    Lb + LW + t * 8192 + (et * 16 + il) * 128
                       + (((ks * 4 + kg) ^ (il & 7)) << 4));
        }
    }
    asm volatile("s_waitcnt lgkmcnt(0)" ::: "memory");
    __builtin_amdgcn_sched_barrier(0);
    __builtin_amdgcn_s_barrier();        // W reads done -> region reusable (P/S2/E2)

    // ---------------- main loop: 8 i-tiles, ONE barrier each ----------------
    #pragma unroll
    for (int k = 0; k < 8; ++k) {
        const float* Sc = (const float*)(Lb + SO[k % 3]);
        const int*   Ec = (const int*)  (Lb + EO[k % 3]);
        __bf16*      Pc = (__bf16*)     (Lb + ((k & 1) ? LP1 : LP0));

        // a) stage tile k+2 (retired at barrier k+1 -> ~1.5 iters of cover)
        if (k < 6) {
            const int i2 = ib0 + (k + 2) * 16;
            if (w < 4) {
                const int row = w * 4 + (l >> 4);
                const int c   = (l & 15) ^ (row & 7);
                stage16(src + ((size_t)(b * NN + i2 + row)) * HD + h * ND + c * 4,
                        Lb + SO[(k + 2) % 3] + w * 1024);
            }
            {
                const int row = w * 2 + (l >> 5);
                const int c   = (l & 31) ^ (row & 7);
                stage16(edges + ((size_t)(b * NN + i2 + row)) * NN + j0 + c * 4,
                        Lb + EO[(k + 2) % 3] + w * 1024);
            }
        }

        // b) edge int4 for this iter (staged 2 iters ago, retired at barrier k-1)
        const i32x4 ce = *reinterpret_cast<const i32x4*>(
            Ec + il * 128 + (((w * 4 + kg) ^ (il & 7)) << 2));

        // c) phase 1: P_t[i, e-tile et] for this wave's t-subset
        {
            f32x4 a0 = *reinterpret_cast<const f32x4*>(&Sc[il * ND + (((2 * kg + 0) ^ (il & 7)) << 2)]);
            f32x4 a1 = *reinterpret_cast<const f32x4*>(&Sc[il * ND + (((2 * kg + 1) ^ (il & 7)) << 2)]);
            f32x4 a2 = *reinterpret_cast<const f32x4*>(&Sc[il * ND + (((8 + 2 * kg) ^ (il & 7)) << 2)]);
            f32x4 a3 = *reinterpret_cast<const f32x4*>(&Sc[il * ND + (((9 + 2 * kg) ^ (il & 7)) << 2)]);
            bf16x8 bf0 = cvt8(a0, a1);
            bf16x8 bf1 = cvt8(a2, a3);
            __builtin_amdgcn_s_setprio(1);
            #pragma unroll
            for (int tt = 0; tt < 3; ++tt) {
                if (tt < ntl) {
                    const int t = t0 + tt;
                    // A = W^T rows (m=e), B = src (n=i): lane holds e=et*16+kg*4+r, i=il
                    f32x4 pacc = {0.f, 0.f, 0.f, 0.f};
                    pacc = __builtin_amdgcn_mfma_f32_16x16x32_bf16(wa[tt][0], bf0, pacc, 0, 0, 0);
                    pacc = __builtin_amdgcn_mfma_f32_16x16x32_bf16(wa[tt][1], bf1, pacc, 0, 0, 0);
                    bf16x4 pk;
                    pk[0] = (__bf16)pacc[0];
                    pk[1] = (__bf16)pacc[1];
                    pk[2] = (__bf16)pacc[2];
                    pk[3] = (__bf16)pacc[3];
                    const int elem = (et * 16 + kg * 4) ^ ((il & 7) << 3);
                    *reinterpret_cast<bf16x4*>(Pc + t * 1024 + il * ND + elem) = pk;
                }
            }
            __builtin_amdgcn_s_setprio(0);
        }

        // d) counted-wait barrier (per-wave counts, wave-uniform branches):
        //    waves 0-3 staged S+E this iter; waves 4-7 staged E only; tail: none.
        if (k < 6) {
            if (w < 4) { asm volatile("s_waitcnt vmcnt(3) lgkmcnt(0)" ::: "memory"); }
            else       { asm volatile("s_waitcnt vmcnt(2) lgkmcnt(0)" ::: "memory"); }
        } else {
            asm volatile("s_waitcnt vmcnt(1) lgkmcnt(0)" ::: "memory");
        }
        __builtin_amdgcn_sched_barrier(0);
        __builtin_amdgcn_s_barrier();

        // e) phase 2: this wave's 16-j tile vs all 16 i of the tile
        {
            bf16x8 pa[NT][2];
            #pragma unroll
            for (int t = 0; t < NT; ++t)
                #pragma unroll
                for (int ks = 0; ks < 2; ++ks)
                    pa[t][ks] = *reinterpret_cast<const bf16x8*>(
                        Pc + t * 1024 + il * ND + (((ks * 4 + kg) ^ (il & 7)) << 3));

            __builtin_amdgcn_s_setprio(1);
            f32x4 acc[NT];
            #pragma unroll
            for (int t = 0; t < NT; ++t) {
                acc[t] = (f32x4){0.f, 0.f, 0.f, 0.f};
                // A = dst rows (m=j), B = P (n=i): lane holds j=w*16+kg*4+r, i=il
                acc[t] = __builtin_amdgcn_mfma_f32_16x16x32_bf16(cb0, pa[t][0], acc[t], 0, 0, 0);
                acc[t] = __builtin_amdgcn_mfma_f32_16x16x32_bf16(cb1, pa[t][1], acc[t], 0, 0, 0);
            }
            __builtin_amdgcn_s_setprio(0);

            f32x4 o;
            #pragma unroll
            for (int r = 0; r < 4; ++r) {
                const int ev = ce[r];
                float x;
                if (ev < 0) { x = -1e10f; }
                else {
                    x = (ev == 0) ? acc[0][r]
                      : (ev == 1) ? acc[1][r]
                      : (ev == 2) ? acc[2][r]
                      : (ev == 3) ? acc[3][r]
                      :             acc[4][r];
                }
                o[r] = (x >= 0.f) ? x : 0.2f * x;
            }
            *reinterpret_cast<f32x4*>(
                out + ((size_t)(b * NH + h) * NN + ib0 + k * 16 + il) * NN
                    + j0 + w * 16 + kg * 4) = o;
        }
        // No trailing barrier: next phase1 writes the OTHER P buffer; S/E slot
        // rotation hazards separated by the barrier above; phase2 P-reads drained
        // by the next barrier's lgkmcnt(0).
    }
}

// ---------------- fallback (ws too small): fused 1-wave kernel, araw path ----------------
__global__ __launch_bounds__(64, 3) void mhea_fused_fallback(
    const float* __restrict__ src, const float* __restrict__ dst,
    const float* __restrict__ araw, const int* __restrict__ edges,
    float* __restrict__ out)
{
    __shared__ __bf16 Plds[NT * 16 * 64];

    const int it = blockIdx.x;
    const int h  = blockIdx.y;
    const int b  = blockIdx.z;
    const int i0 = it * 16;

    const int l  = threadIdx.x & 63;
    const int il = l & 15;
    const int kg = l >> 4;

    const float* dbase = dst + (size_t)b * NN * HD + h * ND;
    const int*   erow  = edges + ((size_t)b * NN + i0 + il) * NN;
    const float* sbase = src + (size_t)(b * NN + i0 + il) * HD + h * ND;

    f32x4 s0 = *reinterpret_cast<const f32x4*>(sbase + kg * 8);
    f32x4 s1 = *reinterpret_cast<const f32x4*>(sbase + kg * 8 + 4);
    f32x4 s2 = *reinterpret_cast<const f32x4*>(sbase + 32 + kg * 8);
    f32x4 s3 = *reinterpret_cast<const f32x4*>(sbase + 36 + kg * 8);
    bf16x8 af0 = cvt8(s0, s1);
    bf16x8 af1 = cvt8(s2, s3);

    #pragma unroll
    for (int t = 0; t < NT; ++t) {
        #pragma unroll
        for (int et = 0; et < 4; ++et) {
            bf16x8 w0, w1;
            #pragma unroll
            for (int jj = 0; jj < 8; ++jj) {
                const int ee = et * 16 + il;
                w0[jj] = (__bf16)araw[((size_t)(h * ND + kg * 8 + jj) * ND + ee) * NT + t];
                w1[jj] = (__bf16)araw[((size_t)(h * ND + kg * 8 + jj + 32) * ND + ee) * NT + t];
            }
            f32x4 pacc = {0.f, 0.f, 0.f, 0.f};
            pacc = __builtin_amdgcn_mfma_f32_16x16x32_bf16(w0, af0, pacc, 0, 0, 0);
            pacc = __builtin_amdgcn_mfma_f32_16x16x32_bf16(w1, af1, pacc, 0, 0, 0);
            bf16x4 pk;
            pk[0] = (__bf16)pacc[0];
            pk[1] = (__bf16)pacc[1];
            pk[2] = (__bf16)pacc[2];
            pk[3] = (__bf16)pacc[3];
            const int elem = (et * 16 + kg * 4) ^ ((il & 7) << 3);
            *reinterpret_cast<bf16x4*>(&Plds[t * 1024 + il * 64 + elem]) = pk;
        }
    }

    bf16x8 pa[NT][2];
    #pragma unroll
    for (int t = 0; t < NT; ++t) {
        #pragma unroll
        for (int ks = 0; ks < 2; ++ks) {
            const int elem = (ks * 32 + kg * 8) ^ ((il & 7) << 3);
            pa[t][ks] = *reinterpret_cast<const bf16x8*>(&Plds[t * 1024 + il * 64 + elem]);
        }
    }

    float* obase = out + (((size_t)(b * NH + h)) * NN + i0 + il) * NN;

    for (int jt = 0; jt < 16; ++jt) {
        const float* np = dbase + (size_t)(jt * 16 + il) * HD + kg * 8;
        f32x4 d0 = *reinterpret_cast<const f32x4*>(np);
        f32x4 d1 = *reinterpret_cast<const f32x4*>(np + 4);
        f32x4 d2 = *reinterpret_cast<const f32x4*>(np + 32);
        f32x4 d3 = *reinterpret_cast<const f32x4*>(np + 36);
        i32x4 ce = *reinterpret_cast<const i32x4*>(erow + jt * 16 + kg * 4);
        const bf16x8 cb0 = cvt8(d0, d1);
        const bf16x8 cb1 = cvt8(d2, d3);
        f32x4 acc[NT];
        #pragma unroll
        for (int t = 0; t < NT; ++t) {
            acc[t] = (f32x4){0.f, 0.f, 0.f, 0.f};
            acc[t] = __builtin_amdgcn_mfma_f32_16x16x32_bf16(cb0, pa[t][0], acc[t], 0, 0, 0);
            acc[t] = __builtin_amdgcn_mfma_f32_16x16x32_bf16(cb1, pa[t][1], acc[t], 0, 0, 0);
        }
        f32x4 o;
        #pragma unroll
        for (int r = 0; r < 4; ++r) {
            const int ev = ce[r];
            float x;
            if (ev < 0) { x = -1e10f; }
            else {
                x = (ev == 0) ? acc[0][r]
                  : (ev == 1) ? acc[1][r]
                  : (ev == 2) ? acc[2][r]
                  : (ev == 3) ? acc[3][r]
                  :             acc[4][r];
            }
            o[r] = (x >= 0.f) ? x : 0.2f * x;
        }
        *reinterpret_cast<f32x4*>(obase + jt * 16 + kg * 4) = o;
    }
}

extern "C" void kernel_launch(void* const* d_in, const int* in_sizes, int n_in,
                              void* d_out, int out_size, void* d_ws, size_t ws_size,
                              hipStream_t stream) {
    const float* src   = (const float*)d_in[0];
    const float* dst   = (const float*)d_in[1];
    const float* a     = (const float*)d_in[2];
    const int*   edges = (const int*)d_in[3];
    float* out = (float*)d_out;

    const size_t wt_bytes = (size_t)NH * NT * ND * ND * sizeof(__bf16);  // 320 KB

    if (ws_size >= wt_bytes) {
        __bf16* wt = (__bf16*)d_ws;
        const int total = NH * ND * ND * NT;           // 163840
        prep_w_kernel<<<(total / 8 + 255) / 256, 256, 0, stream>>>(a, wt);
        mhea_fused<<<512, 512, 0, stream>>>(src, dst, wt, edges, out);
    } else {
        mhea_fused_fallback<<<dim3(NN / 16, NH, NB), 64, 0, stream>>>(
            src, dst, a, edges, out);
    }
}